// Round 8
// baseline (7628.227 us; speedup 1.0000x reference)
//
#include <hip/hip_runtime.h>

// ---------------- problem constants ----------------
constexpr int nB = 8, nS = 512, nH = 8, nD = 64, nHID = 512;
constexpr int THOP = 32, TEDGE = 16;
constexpr float SCALE = 0.125f;   // 64^-0.5
constexpr float NEGINF = -30000.0f;

// ---------------- module-scope scratch (all fp32) ----------------
__device__ float g_qh[(size_t)nB * nH * nS * nD];   // [bh][s][d]
__device__ float g_kh[(size_t)nB * nH * nS * nD];   // [bh][s][d]
__device__ float g_vh[(size_t)nB * nH * nS * nD];   // [bh][s][d]
__device__ float g_x[(size_t)nB * nS * nHID];       // [b*s][hid]
// 0:dist64 1:edge64 2:mmode 3:fmode ; dtype flags (0=bf16,1=fp32):
// 4:q 5:k 6:v 7:qhe 8:qee 9:khe 10:kee 11:vhe 12:vee
// 13:Wq 14:bq 15:Wk 16:bk 17:Wv 18:bv 19:Wo 20:bo
__device__ int g_flags[32];

// adaptive scalar load: bf16 or fp32 element i
__device__ __forceinline__ float ldf(const void* p, int isf32, size_t i) {
  if (isf32) return ((const float*)p)[i];
  unsigned int w = (unsigned int)(((const unsigned short*)p)[i]) << 16;
  return __uint_as_float(w);
}

// ---------------- bool-encoding detection ----------------
__device__ int detect_bool_mode(const unsigned char* p) {
  if (p[0] == 0x80 && p[1] == 0x3F) return 2;   // bf16 (1.0 = 0x3F80)
  if (p[0] == 0x00 && p[1] == 0x3C) return 4;   // fp16
  if (p[0] == 0x00 && p[3] == 0x3F) return 3;   // fp32
  for (int i = 0; i < 64; i += 4)               // u8 vs int32
    if (p[i + 1] | p[i + 2] | p[i + 3]) return 1;
  return 0;                                     // int32
}
__device__ __forceinline__ bool bool_at(const unsigned char* p, int mode, size_t i) {
  switch (mode) {
    case 0: return ((const int*)p)[i] != 0;
    case 1: return p[i] != 0;
    case 3: return ((const float*)p)[i] != 0.f;
    default: return ((const unsigned short*)p)[i] != 0;  // bf16/fp16
  }
}

// ---------------- one-block detection of all runtime encodings --------------
__global__ __launch_bounds__(256) void detect_all(
    const void* q, const void* k, const void* v,
    const void* qhe, const void* qee, const void* khe, const void* kee,
    const void* vhe, const void* vee,
    const int* dist, const int* edge,
    const unsigned char* mraw, const unsigned char* fraw,
    const void* Wq, const void* bq, const void* Wk, const void* bk,
    const void* Wv, const void* bv, const void* Wo, const void* bo) {
  __shared__ float sred[256];
  __shared__ int nz[2];
  const int tid = threadIdx.x;

  auto redmax = [&](float m) -> float {
    sred[tid] = m;
    __syncthreads();
    for (int s = 128; s > 0; s >>= 1) {
      if (tid < s) sred[tid] = fmaxf(sred[tid], sred[tid + s]);
      __syncthreads();
    }
    float r = sred[0];
    __syncthreads();
    return r;
  };
  // max |x| over n halfwords read as bf16 (NaN -> 1e20). fp32 arrays show
  // random-exponent garbage in their low halves -> max >> 1e3.
  auto halfscan = [&](const void* p, int n) -> float {
    const unsigned short* u = (const unsigned short*)p;
    float m = 0.f;
    for (int i = tid; i < n; i += 256) {
      float x = __uint_as_float((unsigned int)u[i] << 16);
      if (x != x) x = 1e20f;
      m = fmaxf(m, fabsf(x));
    }
    return redmax(m);
  };

  const void* arrs[17] = {q, k, v, qhe, qee, khe, kee, vhe, vee,
                          Wq, bq, Wk, bk, Wv, bv, Wo, bo};
  const int ns[17] = {2097152, 2097152, 2097152, 8192, 8192, 8192, 8192, 8192,
                      8192, 262144, 512, 262144, 512, 262144, 512, 262144, 512};
  float mx[17];
  for (int i = 0; i < 17; ++i) mx[i] = halfscan(arrs[i], ns[i]);

  if (tid < 2) nz[tid] = 0;
  __syncthreads();
  int a = 0, b2 = 0;
  for (int i = tid; i < 4096; i += 256) {
    a |= dist[2 * i + 1];   // high words if int64 (values 0..31 -> all zero)
    b2 |= edge[2 * i + 1];
  }
  if (a) atomicOr(&nz[0], 1);
  if (b2) atomicOr(&nz[1], 1);
  __syncthreads();

  if (tid == 0) {
    g_flags[0] = (nz[0] == 0);          // dist is int64
    g_flags[1] = (nz[1] == 0);          // edge is int64
    g_flags[2] = detect_bool_mode(mraw);
    g_flags[3] = detect_bool_mode(fraw);
    for (int i = 0; i < 17; ++i) g_flags[4 + i] = (mx[i] > 1e3f) ? 1 : 0;
  }
}

// ------- projection: dst[bh][s][d] = A[m,:] @ W[:,n] + bias[n]  (fp32) ------
__global__ __launch_bounds__(256) void proj_gemm(
    const void* __restrict__ A, int aFlag,
    const void* __restrict__ W, int wFlag,
    const void* __restrict__ bias, int bFlag,
    float* __restrict__ dst) {
  const int aF = g_flags[aFlag], wF = g_flags[wFlag], bF = g_flags[bFlag];
  const int tx = threadIdx.x & 63, ty = threadIdx.x >> 6;
  const int m = blockIdx.y * 4 + ty;
  const int n = blockIdx.x * 64 + tx;
  float acc = 0.f;
#pragma unroll 4
  for (int k = 0; k < 512; ++k)
    acc += ldf(A, aF, (size_t)m * 512 + k) * ldf(W, wF, (size_t)k * 512 + n);
  acc += ldf(bias, bF, n);
  const int b = m >> 9, s = m & 511, h = n >> 6, d = n & 63;
  dst[(((size_t)(b * nH + h) * nS) + s) * nD + d] = acc;
}

// ------- output GEMM: out[m,n] = g_x[m,:] @ Wo[:,n] + bo[n] -> FP32 ---------
__global__ __launch_bounds__(256) void out_gemm(
    const void* __restrict__ W, const void* __restrict__ bias,
    float* __restrict__ out) {
  const int wFl = g_flags[19], bFl = g_flags[20];
  const int tx = threadIdx.x & 63, ty = threadIdx.x >> 6;
  const int m = blockIdx.y * 4 + ty;
  const int n = blockIdx.x * 64 + tx;
  float acc = 0.f;
#pragma unroll 4
  for (int k = 0; k < 512; ++k)
    acc += g_x[(size_t)m * 512 + k] * ldf(W, wFl, (size_t)k * 512 + n);
  acc += ldf(bias, bFl, n);
  out[(size_t)m * 512 + n] = acc;   // fp32 store — the round-0..7 bug was bf16 here
}

// ---------------- fused attention: one block per (bh, 16-query tile) --------
__global__ __launch_bounds__(256) void attn_kernel(
    const void* __restrict__ qhe, const void* __restrict__ qee,
    const void* __restrict__ khe, const void* __restrict__ kee,
    const int* __restrict__ dist, const int* __restrict__ edge,
    const unsigned char* __restrict__ mraw, const unsigned char* __restrict__ fraw,
    const void* __restrict__ vhe, const void* __restrict__ vee) {
  __shared__ float qtile[16][64];
  __shared__ float ktile[16][64];
  __shared__ float sc[16][516];
  __shared__ float chop_s[16][THOP];
  __shared__ float cedge_s[16][TEDGE];
  __shared__ float vha_s[16][THOP];
  __shared__ float vea_s[16][TEDGE];
  __shared__ float red[16][16];
  __shared__ float rowmax_s[16], rowinv_s[16];
  __shared__ unsigned char d8[16][512];
  __shared__ unsigned char e8[16][512];

  const int qt = blockIdx.x, bh = blockIdx.y;
  const int b = bh >> 3, h = bh & 7;
  const int q0 = qt * 16;
  const int tid = threadIdx.x;

  const int d64 = g_flags[0], e64 = g_flags[1];
  const int mmode = g_flags[2], fmode = g_flags[3];
  const int fqhe = g_flags[7], fqee = g_flags[8];
  const int fkhe = g_flags[9], fkee = g_flags[10];
  const int fvhe = g_flags[11], fvee = g_flags[12];

  // stage query-row tiles of qh and kh; zero bins
  for (int i = tid; i < 1024; i += 256) {
    const int r = i >> 6, c = i & 63;
    qtile[r][c] = g_qh[((size_t)bh * nS + q0 + r) * nD + c];
    ktile[r][c] = g_kh[((size_t)bh * nS + q0 + r) * nD + c];
  }
  {
    const int r = tid >> 5, c = tid & 31;
    vha_s[r][c] = 0.f;
    vha_s[8 + r][c] = 0.f;
    vea_s[tid >> 4][tid & 15] = 0.f;
  }
  __syncthreads();

  // ---- Phase 0: chop[q][t], cedge[q][t] (VALU dots, fp32) ----
  {
    const int q = tid >> 4, c = tid & 15;
#pragma unroll
    for (int tt = 0; tt < 2; ++tt) {
      const int t = c + tt * 16;
      float s1 = 0.f;
      for (int d = 0; d < 64; ++d) {
        const size_t e = (size_t)t * nHID + h * 64 + d;
        s1 += qtile[q][d] * ldf(qhe, fqhe, e) + ktile[q][d] * ldf(khe, fkhe, e);
      }
      chop_s[q][t] = s1;
    }
    float s2 = 0.f;
    for (int d = 0; d < 64; ++d) {
      const size_t e = (size_t)c * nHID + h * 64 + d;
      s2 += qtile[q][d] * ldf(qee, fqee, e) + ktile[q][d] * ldf(kee, fkee, e);
    }
    cedge_s[q][c] = s2;
  }
  __syncthreads();

  // ---- Phase A: scores = (QK^T + gathered bias) * SCALE, masked ----
#pragma unroll
  for (int kk = 0; kk < 2; ++kk) {
    const int key = tid + kk * 256;
    float acc16[16];
#pragma unroll
    for (int q = 0; q < 16; ++q) acc16[q] = 0.f;
    const size_t krow = ((size_t)bh * nS + key) * nD;
    for (int d = 0; d < 64; ++d) {
      const float kv = g_kh[krow + d];
#pragma unroll
      for (int q = 0; q < 16; ++q) acc16[q] += qtile[q][d] * kv;
    }
    const bool kmask = bool_at(mraw, mmode, (size_t)b * nS + key);
#pragma unroll
    for (int q = 0; q < 16; ++q) {
      const size_t off = ((size_t)b * nS + q0 + q) * nS + key;
      const int dv = (d64 ? dist[2 * off] : dist[off]) & (THOP - 1);
      const int ev = (e64 ? edge[2 * off] : edge[off]) & (TEDGE - 1);
      d8[q][key] = (unsigned char)dv;
      e8[q][key] = (unsigned char)ev;
      const float s = (acc16[q] + chop_s[q][dv] + cedge_s[q][ev]) * SCALE;
      const bool keep = (h < 4) ? kmask : bool_at(fraw, fmode, off);
      sc[q][key] = keep ? s : NEGINF;
    }
  }
  __syncthreads();

  // ---- Phase B: softmax (unnormalized) + bin scatter ----
  {
    const int row = tid >> 4, c = tid & 15;
    float m = NEGINF;
#pragma unroll
    for (int i = 0; i < 32; ++i) m = fmaxf(m, sc[row][c + 16 * i]);
    red[row][c] = m;
    __syncthreads();
    if (c == 0) {
      float mm = red[row][0];
#pragma unroll
      for (int i = 1; i < 16; ++i) mm = fmaxf(mm, red[row][i]);
      rowmax_s[row] = mm;
    }
    __syncthreads();
    const float M = rowmax_s[row];
    float sum = 0.f;
#pragma unroll
    for (int i = 0; i < 32; ++i) {
      const int kx = c + 16 * i;
      const float p = __expf(sc[row][kx] - M);  // <= 1 always
      sc[row][kx] = p;
      sum += p;
      atomicAdd(&vha_s[row][d8[row][kx]], p);
      atomicAdd(&vea_s[row][e8[row][kx]], p);
    }
    red[row][c] = sum;
    __syncthreads();
    if (c == 0) {
      float ss = 0.f;
#pragma unroll
      for (int i = 0; i < 16; ++i) ss += red[row][i];
      rowinv_s[row] = 1.0f / ss;
    }
  }
  __syncthreads();

  // ---- Phase C: x = (P@V + vha@vhopE + vea@vedgeE) / rowsum ----
  {
    const int qq = tid >> 6, d = tid & 63;
    float a4[4] = {0.f, 0.f, 0.f, 0.f};
    const size_t vbase = (size_t)bh * nS * nD + d;
    for (int k = 0; k < 512; ++k) {
      const float vv = g_vh[vbase + (size_t)k * nD];
#pragma unroll
      for (int j = 0; j < 4; ++j) a4[j] += sc[qq + j * 4][k] * vv;
    }
#pragma unroll
    for (int j = 0; j < 4; ++j) {
      const int q = qq + j * 4;
      float val = a4[j];
      for (int t = 0; t < THOP; ++t)
        val += vha_s[q][t] * ldf(vhe, fvhe, (size_t)t * nHID + h * 64 + d);
      for (int t = 0; t < TEDGE; ++t)
        val += vea_s[q][t] * ldf(vee, fvee, (size_t)t * nHID + h * 64 + d);
      val *= rowinv_s[q];
      g_x[((size_t)b * nS + q0 + q) * nHID + h * 64 + d] = val;
    }
  }
}

// ---------------- launcher ----------------
extern "C" void kernel_launch(void* const* d_in, const int* in_sizes, int n_in,
                              void* d_out, int out_size, void* d_ws, size_t ws_size,
                              hipStream_t stream) {
  const void* q   = d_in[0];
  const void* k   = d_in[1];
  const void* v   = d_in[2];
  const void* qhe = d_in[3];
  const void* qee = d_in[4];
  const void* khe = d_in[5];
  const void* kee = d_in[6];
  const void* vhe = d_in[7];
  const void* vee = d_in[8];
  const int* dist = (const int*)d_in[9];
  const int* edge = (const int*)d_in[10];
  const unsigned char* mraw = (const unsigned char*)d_in[11];
  const unsigned char* fraw = (const unsigned char*)d_in[12];
  const void* Wq = d_in[13];
  const void* bq = d_in[14];
  const void* Wk = d_in[15];
  const void* bk = d_in[16];
  const void* Wv = d_in[17];
  const void* bv = d_in[18];
  const void* Wo = d_in[19];
  const void* bo = d_in[20];

  detect_all<<<1, 256, 0, stream>>>(q, k, v, qhe, qee, khe, kee, vhe, vee,
                                    dist, edge, mraw, fraw,
                                    Wq, bq, Wk, bk, Wv, bv, Wo, bo);
  float* qh_d; hipGetSymbolAddress((void**)&qh_d, HIP_SYMBOL(g_qh));
  float* kh_d; hipGetSymbolAddress((void**)&kh_d, HIP_SYMBOL(g_kh));
  float* vh_d; hipGetSymbolAddress((void**)&vh_d, HIP_SYMBOL(g_vh));
  proj_gemm<<<dim3(8, 1024), 256, 0, stream>>>(q, 4, Wq, 13, bq, 14, qh_d);
  proj_gemm<<<dim3(8, 1024), 256, 0, stream>>>(k, 5, Wk, 15, bk, 16, kh_d);
  proj_gemm<<<dim3(8, 1024), 256, 0, stream>>>(v, 6, Wv, 17, bv, 18, vh_d);
  attn_kernel<<<dim3(32, 64), 256, 0, stream>>>(qhe, qee, khe, kee, dist, edge,
                                                mraw, fraw, vhe, vee);
  out_gemm<<<dim3(8, 1024), 256, 0, stream>>>(Wo, bo, (float*)d_out);
}

// Round 9
// 1265.327 us; speedup vs baseline: 6.0287x; 6.0287x over previous
//
#include <hip/hip_runtime.h>

// ---------------- problem constants ----------------
constexpr int nB = 8, nS = 512, nH = 8, nD = 64, nHID = 512;
constexpr int THOP = 32, TEDGE = 16;
constexpr float SCALE = 0.125f;   // 64^-0.5
constexpr float NEGINF = -30000.0f;

// ---------------- module-scope scratch (all fp32) ----------------
__device__ float g_qh[(size_t)nB * nH * nS * nD];   // [bh][s][d]
__device__ float g_kh[(size_t)nB * nH * nS * nD];   // [bh][s][d]
__device__ float g_vh[(size_t)nB * nH * nS * nD];   // [bh][s][d]
__device__ float g_x[(size_t)nB * nS * nHID];       // [b*s][hid]
// 0:dist64 1:edge64 2:mmode 3:fmode ; dtype flags (0=bf16,1=fp32):
// 4..20 = q,k,v,qhe,qee,khe,kee,vhe,vee,Wq,bq,Wk,bk,Wv,bv,Wo,bo ; 21 = const 1
__device__ int g_flags[32];

// adaptive scalar load: bf16 or fp32 element i
__device__ __forceinline__ float ldf(const void* p, int isf32, size_t i) {
  if (isf32) return ((const float*)p)[i];
  unsigned int w = (unsigned int)(((const unsigned short*)p)[i]) << 16;
  return __uint_as_float(w);
}

// ---------------- bool-encoding detection ----------------
__device__ int detect_bool_mode(const unsigned char* p) {
  if (p[0] == 0x80 && p[1] == 0x3F) return 2;   // bf16 (1.0 = 0x3F80)
  if (p[0] == 0x00 && p[1] == 0x3C) return 4;   // fp16
  if (p[0] == 0x00 && p[3] == 0x3F) return 3;   // fp32
  for (int i = 0; i < 64; i += 4)               // u8 vs int32
    if (p[i + 1] | p[i + 2] | p[i + 3]) return 1;
  return 0;                                     // int32
}
__device__ __forceinline__ bool bool_at(const unsigned char* p, int mode, size_t i) {
  switch (mode) {
    case 0: return ((const int*)p)[i] != 0;
    case 1: return p[i] != 0;
    case 3: return ((const float*)p)[i] != 0.f;
    default: return ((const unsigned short*)p)[i] != 0;  // bf16/fp16
  }
}

// -------- parallel detection: one block per array/task, sampled -------------
__global__ __launch_bounds__(256) void detect_all(
    const void* q, const void* k, const void* v,
    const void* qhe, const void* qee, const void* khe, const void* kee,
    const void* vhe, const void* vee,
    const int* dist, const int* edge,
    const unsigned char* mraw, const unsigned char* fraw,
    const void* Wq, const void* bq, const void* Wk, const void* bk,
    const void* Wv, const void* bv, const void* Wo, const void* bo) {
  __shared__ float sred[256];
  __shared__ int nzs;
  const int tid = threadIdx.x;
  const int blk = blockIdx.x;

  if (blk < 17) {
    const void* arrs[17] = {q, k, v, qhe, qee, khe, kee, vhe, vee,
                            Wq, bq, Wk, bk, Wv, bv, Wo, bo};
    const int full[17] = {2097152, 2097152, 2097152, 8192, 8192, 8192, 8192,
                          8192, 8192, 262144, 512, 262144, 512, 262144, 512,
                          262144, 512};
    const int n = full[blk] < 16384 ? full[blk] : 16384;   // sampled scan
    const unsigned short* u = (const unsigned short*)arrs[blk];
    float m = 0.f;
    for (int i = tid; i < n; i += 256) {
      float x = __uint_as_float((unsigned int)u[i] << 16);
      if (x != x) x = 1e20f;
      m = fmaxf(m, fabsf(x));
    }
    sred[tid] = m;
    __syncthreads();
    for (int s = 128; s > 0; s >>= 1) {
      if (tid < s) sred[tid] = fmaxf(sred[tid], sred[tid + s]);
      __syncthreads();
    }
    if (tid == 0) g_flags[4 + blk] = (sred[0] > 1e3f) ? 1 : 0;
  } else if (blk == 17 || blk == 18) {
    const int* p = (blk == 17) ? dist : edge;
    if (tid == 0) nzs = 0;
    __syncthreads();
    int a = 0;
    for (int i = tid; i < 4096; i += 256) a |= p[2 * i + 1];
    if (a) atomicOr(&nzs, 1);
    __syncthreads();
    if (tid == 0) g_flags[blk - 17] = (nzs == 0);   // all-zero high words -> int64
  } else {
    if (tid == 0) {
      g_flags[2] = detect_bool_mode(mraw);
      g_flags[3] = detect_bool_mode(fraw);
      g_flags[21] = 1;                              // const: g_x is fp32
    }
  }
}

// -------- LDS-tiled fp32 GEMM: C[m,n] = A[m,:] @ W[:,n] + bias[n] -----------
// 64x64 tile / block, 256 threads, 4x4 micro-tile.
// mode 0..2: dst head-split [bh][s][d]; mode 3: plain [m][n].
__global__ __launch_bounds__(256) void gemm_tiled(
    const void* __restrict__ A, int aFlag,
    const void* __restrict__ W, int wFlag,
    const void* __restrict__ bias, int bFlag,
    float* __restrict__ dst, int mode) {
  __shared__ float As[32][65];   // [k][m] (transposed) — conflict-free staging
  __shared__ float Ws[32][65];   // [k][n]
  const int aF = g_flags[aFlag], wF = g_flags[wFlag], bF = g_flags[bFlag];
  const int tid = threadIdx.x;
  const int m0 = blockIdx.y * 64, n0 = blockIdx.x * 64;
  const int ti = tid & 15, tj = tid >> 4;   // ti: n-quad, tj: m-quad
  float acc[4][4] = {{0.f}};

  for (int k0 = 0; k0 < 512; k0 += 32) {
    __syncthreads();
#pragma unroll
    for (int i = 0; i < 8; ++i) {
      const int idx = tid + i * 256;            // 0..2047
      const int r = idx >> 5, c = idx & 31;     // A tile: 64 m x 32 k
      As[c][r] = ldf(A, aF, (size_t)(m0 + r) * 512 + k0 + c);
      const int kr = idx >> 6, n = idx & 63;    // W tile: 32 k x 64 n
      Ws[kr][n] = ldf(W, wF, (size_t)(k0 + kr) * 512 + n0 + n);
    }
    __syncthreads();
#pragma unroll
    for (int kc = 0; kc < 32; ++kc) {
      const float a0 = As[kc][tj * 4 + 0], a1 = As[kc][tj * 4 + 1];
      const float a2 = As[kc][tj * 4 + 2], a3 = As[kc][tj * 4 + 3];
      const float b0 = Ws[kc][ti * 4 + 0], b1 = Ws[kc][ti * 4 + 1];
      const float b2 = Ws[kc][ti * 4 + 2], b3 = Ws[kc][ti * 4 + 3];
      acc[0][0] += a0 * b0; acc[0][1] += a0 * b1; acc[0][2] += a0 * b2; acc[0][3] += a0 * b3;
      acc[1][0] += a1 * b0; acc[1][1] += a1 * b1; acc[1][2] += a1 * b2; acc[1][3] += a1 * b3;
      acc[2][0] += a2 * b0; acc[2][1] += a2 * b1; acc[2][2] += a2 * b2; acc[2][3] += a2 * b3;
      acc[3][0] += a3 * b0; acc[3][1] += a3 * b1; acc[3][2] += a3 * b2; acc[3][3] += a3 * b3;
    }
  }
#pragma unroll
  for (int mi = 0; mi < 4; ++mi)
#pragma unroll
    for (int ni = 0; ni < 4; ++ni) {
      const int m = m0 + tj * 4 + mi;
      const int n = n0 + ti * 4 + ni;
      const float v2 = acc[mi][ni] + ldf(bias, bF, n);
      if (mode == 3) {
        dst[(size_t)m * 512 + n] = v2;
      } else {
        const int b = m >> 9, s = m & 511, h = n >> 6, d = n & 63;
        dst[(((size_t)(b * nH + h) * nS) + s) * nD + d] = v2;
      }
    }
}

// ---------------- fused attention: one block per (bh, 16-query tile) --------
__global__ __launch_bounds__(256) void attn_kernel(
    const void* __restrict__ qhe, const void* __restrict__ qee,
    const void* __restrict__ khe, const void* __restrict__ kee,
    const int* __restrict__ dist, const int* __restrict__ edge,
    const unsigned char* __restrict__ mraw, const unsigned char* __restrict__ fraw,
    const void* __restrict__ vhe, const void* __restrict__ vee) {
  __shared__ float qtile[16][64];
  __shared__ float ktile[16][64];
  __shared__ float sc[16][516];
  __shared__ float chop_s[16][THOP];
  __shared__ float cedge_s[16][TEDGE];
  __shared__ float vha_s[16][THOP];
  __shared__ float vea_s[16][TEDGE];
  __shared__ float red[16][16];
  __shared__ float rowmax_s[16], rowinv_s[16];
  __shared__ unsigned char d8[16][512];
  __shared__ unsigned char e8[16][512];

  const int qt = blockIdx.x, bh = blockIdx.y;
  const int b = bh >> 3, h = bh & 7;
  const int q0 = qt * 16;
  const int tid = threadIdx.x;

  const int d64 = g_flags[0], e64 = g_flags[1];
  const int mmode = g_flags[2], fmode = g_flags[3];
  const int fqhe = g_flags[7], fqee = g_flags[8];
  const int fkhe = g_flags[9], fkee = g_flags[10];
  const int fvhe = g_flags[11], fvee = g_flags[12];

  for (int i = tid; i < 1024; i += 256) {
    const int r = i >> 6, c = i & 63;
    qtile[r][c] = g_qh[((size_t)bh * nS + q0 + r) * nD + c];
    ktile[r][c] = g_kh[((size_t)bh * nS + q0 + r) * nD + c];
  }
  {
    const int r = tid >> 5, c = tid & 31;
    vha_s[r][c] = 0.f;
    vha_s[8 + r][c] = 0.f;
    vea_s[tid >> 4][tid & 15] = 0.f;
  }
  __syncthreads();

  // ---- Phase 0: chop[q][t], cedge[q][t] ----
  {
    const int q = tid >> 4, c = tid & 15;
#pragma unroll
    for (int tt = 0; tt < 2; ++tt) {
      const int t = c + tt * 16;
      float s1 = 0.f;
      for (int d = 0; d < 64; ++d) {
        const size_t e = (size_t)t * nHID + h * 64 + d;
        s1 += qtile[q][d] * ldf(qhe, fqhe, e) + ktile[q][d] * ldf(khe, fkhe, e);
      }
      chop_s[q][t] = s1;
    }
    float s2 = 0.f;
    for (int d = 0; d < 64; ++d) {
      const size_t e = (size_t)c * nHID + h * 64 + d;
      s2 += qtile[q][d] * ldf(qee, fqee, e) + ktile[q][d] * ldf(kee, fkee, e);
    }
    cedge_s[q][c] = s2;
  }
  __syncthreads();

  // ---- Phase A: scores = (QK^T + gathered bias) * SCALE, masked ----
#pragma unroll
  for (int kk = 0; kk < 2; ++kk) {
    const int key = tid + kk * 256;
    float acc16[16];
#pragma unroll
    for (int q = 0; q < 16; ++q) acc16[q] = 0.f;
    const size_t krow = ((size_t)bh * nS + key) * nD;
    for (int d = 0; d < 64; ++d) {
      const float kv = g_kh[krow + d];
#pragma unroll
      for (int q = 0; q < 16; ++q) acc16[q] += qtile[q][d] * kv;
    }
    const bool kmask = bool_at(mraw, mmode, (size_t)b * nS + key);
#pragma unroll
    for (int q = 0; q < 16; ++q) {
      const size_t off = ((size_t)b * nS + q0 + q) * nS + key;
      const int dv = (d64 ? dist[2 * off] : dist[off]) & (THOP - 1);
      const int ev = (e64 ? edge[2 * off] : edge[off]) & (TEDGE - 1);
      d8[q][key] = (unsigned char)dv;
      e8[q][key] = (unsigned char)ev;
      const float s = (acc16[q] + chop_s[q][dv] + cedge_s[q][ev]) * SCALE;
      const bool keep = (h < 4) ? kmask : bool_at(fraw, fmode, off);
      sc[q][key] = keep ? s : NEGINF;
    }
  }
  __syncthreads();

  // ---- Phase B: softmax (unnormalized) + bin scatter ----
  {
    const int row = tid >> 4, c = tid & 15;
    float m = NEGINF;
#pragma unroll
    for (int i = 0; i < 32; ++i) m = fmaxf(m, sc[row][c + 16 * i]);
    red[row][c] = m;
    __syncthreads();
    if (c == 0) {
      float mm = red[row][0];
#pragma unroll
      for (int i = 1; i < 16; ++i) mm = fmaxf(mm, red[row][i]);
      rowmax_s[row] = mm;
    }
    __syncthreads();
    const float M = rowmax_s[row];
    float sum = 0.f;
#pragma unroll
    for (int i = 0; i < 32; ++i) {
      const int kx = c + 16 * i;
      const float p = __expf(sc[row][kx] - M);
      sc[row][kx] = p;
      sum += p;
      atomicAdd(&vha_s[row][d8[row][kx]], p);
      atomicAdd(&vea_s[row][e8[row][kx]], p);
    }
    red[row][c] = sum;
    __syncthreads();
    if (c == 0) {
      float ss = 0.f;
#pragma unroll
      for (int i = 0; i < 16; ++i) ss += red[row][i];
      rowinv_s[row] = 1.0f / ss;
    }
  }
  __syncthreads();

  // ---- Phase C: x = (P@V + vha@vhopE + vea@vedgeE) / rowsum ----
  {
    const int qq = tid >> 6, d = tid & 63;
    float a4[4] = {0.f, 0.f, 0.f, 0.f};
    const size_t vbase = (size_t)bh * nS * nD + d;
    for (int k = 0; k < 512; ++k) {
      const float vv = g_vh[vbase + (size_t)k * nD];
#pragma unroll
      for (int j = 0; j < 4; ++j) a4[j] += sc[qq + j * 4][k] * vv;
    }
#pragma unroll
    for (int j = 0; j < 4; ++j) {
      const int q = qq + j * 4;
      float val = a4[j];
      for (int t = 0; t < THOP; ++t)
        val += vha_s[q][t] * ldf(vhe, fvhe, (size_t)t * nHID + h * 64 + d);
      for (int t = 0; t < TEDGE; ++t)
        val += vea_s[q][t] * ldf(vee, fvee, (size_t)t * nHID + h * 64 + d);
      val *= rowinv_s[q];
      g_x[((size_t)b * nS + q0 + q) * nHID + h * 64 + d] = val;
    }
  }
}

// ---------------- launcher ----------------
extern "C" void kernel_launch(void* const* d_in, const int* in_sizes, int n_in,
                              void* d_out, int out_size, void* d_ws, size_t ws_size,
                              hipStream_t stream) {
  const void* q   = d_in[0];
  const void* k   = d_in[1];
  const void* v   = d_in[2];
  const void* qhe = d_in[3];
  const void* qee = d_in[4];
  const void* khe = d_in[5];
  const void* kee = d_in[6];
  const void* vhe = d_in[7];
  const void* vee = d_in[8];
  const int* dist = (const int*)d_in[9];
  const int* edge = (const int*)d_in[10];
  const unsigned char* mraw = (const unsigned char*)d_in[11];
  const unsigned char* fraw = (const unsigned char*)d_in[12];
  const void* Wq = d_in[13];
  const void* bq = d_in[14];
  const void* Wk = d_in[15];
  const void* bk = d_in[16];
  const void* Wv = d_in[17];
  const void* bv = d_in[18];
  const void* Wo = d_in[19];
  const void* bo = d_in[20];

  detect_all<<<20, 256, 0, stream>>>(q, k, v, qhe, qee, khe, kee, vhe, vee,
                                     dist, edge, mraw, fraw,
                                     Wq, bq, Wk, bk, Wv, bv, Wo, bo);
  float* qh_d; hipGetSymbolAddress((void**)&qh_d, HIP_SYMBOL(g_qh));
  float* kh_d; hipGetSymbolAddress((void**)&kh_d, HIP_SYMBOL(g_kh));
  float* vh_d; hipGetSymbolAddress((void**)&vh_d, HIP_SYMBOL(g_vh));
  float* x_d;  hipGetSymbolAddress((void**)&x_d,  HIP_SYMBOL(g_x));
  gemm_tiled<<<dim3(8, 64), 256, 0, stream>>>(q, 4, Wq, 13, bq, 14, qh_d, 0);
  gemm_tiled<<<dim3(8, 64), 256, 0, stream>>>(k, 5, Wk, 15, bk, 16, kh_d, 1);
  gemm_tiled<<<dim3(8, 64), 256, 0, stream>>>(v, 6, Wv, 17, bv, 18, vh_d, 2);
  attn_kernel<<<dim3(32, 64), 256, 0, stream>>>(qhe, qee, khe, kee, dist, edge,
                                                mraw, fraw, vhe, vee);
  gemm_tiled<<<dim3(8, 64), 256, 0, stream>>>(x_d, 21, Wo, 19, bo, 20,
                                              (float*)d_out, 3);
}

// Round 10
// 1214.610 us; speedup vs baseline: 6.2804x; 1.0418x over previous
//
#include <hip/hip_runtime.h>

// ---------------- problem constants ----------------
constexpr int nB = 8, nS = 512, nH = 8, nD = 64, nHID = 512;
constexpr int THOP = 32, TEDGE = 16;
constexpr float SCALE = 0.125f;   // 64^-0.5
constexpr float NEGINF = -30000.0f;
constexpr int SCLD = 528;         // sc stride: 528%32==16 -> <=2-way (free)

// ---------------- module-scope scratch (all fp32) ----------------
__device__ float g_qh[(size_t)nB * nH * nS * nD];   // [bh][s][d]
__device__ float g_kh[(size_t)nB * nH * nS * nD];   // [bh][s][d]
__device__ float g_vh[(size_t)nB * nH * nS * nD];   // [bh][s][d]
__device__ float g_x[(size_t)nB * nS * nHID];       // [b*s][hid]
// 0:dist64 1:edge64 2:mmode 3:fmode ; dtype flags (0=bf16,1=fp32):
// 4..20 = q,k,v,qhe,qee,khe,kee,vhe,vee,Wq,bq,Wk,bk,Wv,bv,Wo,bo ; 21 = const 1
__device__ int g_flags[32];

// adaptive scalar load: bf16 or fp32 element i
__device__ __forceinline__ float ldf(const void* p, int isf32, size_t i) {
  if (isf32) return ((const float*)p)[i];
  unsigned int w = (unsigned int)(((const unsigned short*)p)[i]) << 16;
  return __uint_as_float(w);
}

// ---------------- bool-encoding detection ----------------
__device__ int detect_bool_mode(const unsigned char* p) {
  if (p[0] == 0x80 && p[1] == 0x3F) return 2;   // bf16 (1.0 = 0x3F80)
  if (p[0] == 0x00 && p[1] == 0x3C) return 4;   // fp16
  if (p[0] == 0x00 && p[3] == 0x3F) return 3;   // fp32
  for (int i = 0; i < 64; i += 4)               // u8 vs int32
    if (p[i + 1] | p[i + 2] | p[i + 3]) return 1;
  return 0;                                     // int32
}
__device__ __forceinline__ bool bool_at(const unsigned char* p, int mode, size_t i) {
  switch (mode) {
    case 0: return ((const int*)p)[i] != 0;
    case 1: return p[i] != 0;
    case 3: return ((const float*)p)[i] != 0.f;
    default: return ((const unsigned short*)p)[i] != 0;  // bf16/fp16
  }
}

// -------- parallel detection: one block per array/task, sampled -------------
__global__ __launch_bounds__(256) void detect_all(
    const void* q, const void* k, const void* v,
    const void* qhe, const void* qee, const void* khe, const void* kee,
    const void* vhe, const void* vee,
    const int* dist, const int* edge,
    const unsigned char* mraw, const unsigned char* fraw,
    const void* Wq, const void* bq, const void* Wk, const void* bk,
    const void* Wv, const void* bv, const void* Wo, const void* bo) {
  __shared__ float sred[256];
  __shared__ int nzs;
  const int tid = threadIdx.x;
  const int blk = blockIdx.x;

  if (blk < 17) {
    const void* arrs[17] = {q, k, v, qhe, qee, khe, kee, vhe, vee,
                            Wq, bq, Wk, bk, Wv, bv, Wo, bo};
    const int full[17] = {2097152, 2097152, 2097152, 8192, 8192, 8192, 8192,
                          8192, 8192, 262144, 512, 262144, 512, 262144, 512,
                          262144, 512};
    const int n = full[blk] < 16384 ? full[blk] : 16384;   // sampled scan
    const unsigned short* u = (const unsigned short*)arrs[blk];
    float m = 0.f;
    for (int i = tid; i < n; i += 256) {
      float x = __uint_as_float((unsigned int)u[i] << 16);
      if (x != x) x = 1e20f;
      m = fmaxf(m, fabsf(x));
    }
    sred[tid] = m;
    __syncthreads();
    for (int s = 128; s > 0; s >>= 1) {
      if (tid < s) sred[tid] = fmaxf(sred[tid], sred[tid + s]);
      __syncthreads();
    }
    if (tid == 0) g_flags[4 + blk] = (sred[0] > 1e3f) ? 1 : 0;
  } else if (blk == 17 || blk == 18) {
    const int* p = (blk == 17) ? dist : edge;
    if (tid == 0) nzs = 0;
    __syncthreads();
    int a = 0;
    for (int i = tid; i < 4096; i += 256) a |= p[2 * i + 1];
    if (a) atomicOr(&nzs, 1);
    __syncthreads();
    if (tid == 0) g_flags[blk - 17] = (nzs == 0);   // all-zero high words -> int64
  } else {
    if (tid == 0) {
      g_flags[2] = detect_bool_mode(mraw);
      g_flags[3] = detect_bool_mode(fraw);
      g_flags[21] = 1;                              // const: g_x is fp32
    }
  }
}

// -------- LDS-tiled fp32 GEMM: C[m,n] = A[m,:] @ W[:,n] + bias[n] -----------
// 64x64 tile / block, 256 threads, 4x4 micro-tile, float4 LDS reads.
__global__ __launch_bounds__(256) void gemm_tiled(
    const void* __restrict__ A, int aFlag,
    const void* __restrict__ W, int wFlag,
    const void* __restrict__ bias, int bFlag,
    float* __restrict__ dst, int mode) {
  __shared__ float As[32][68];   // [k][m]; stride 68 -> 16B-aligned rows
  __shared__ float Ws[32][68];   // [k][n]
  const int aF = g_flags[aFlag], wF = g_flags[wFlag], bF = g_flags[bFlag];
  const int tid = threadIdx.x;
  const int m0 = blockIdx.y * 64, n0 = blockIdx.x * 64;
  const int ti = tid & 15, tj = tid >> 4;   // ti: n-quad, tj: m-quad
  float acc[4][4] = {{0.f}};

  for (int k0 = 0; k0 < 512; k0 += 32) {
    __syncthreads();
#pragma unroll
    for (int i = 0; i < 8; ++i) {
      const int idx = tid + i * 256;            // 0..2047
      const int r = idx >> 5, c = idx & 31;     // A tile: 64 m x 32 k
      As[c][r] = ldf(A, aF, (size_t)(m0 + r) * 512 + k0 + c);
      const int kr = idx >> 6, n = idx & 63;    // W tile: 32 k x 64 n
      Ws[kr][n] = ldf(W, wF, (size_t)(k0 + kr) * 512 + n0 + n);
    }
    __syncthreads();
#pragma unroll
    for (int kc = 0; kc < 32; ++kc) {
      const float4 a = *reinterpret_cast<const float4*>(&As[kc][tj * 4]);
      const float4 bb = *reinterpret_cast<const float4*>(&Ws[kc][ti * 4]);
      acc[0][0] += a.x * bb.x; acc[0][1] += a.x * bb.y; acc[0][2] += a.x * bb.z; acc[0][3] += a.x * bb.w;
      acc[1][0] += a.y * bb.x; acc[1][1] += a.y * bb.y; acc[1][2] += a.y * bb.z; acc[1][3] += a.y * bb.w;
      acc[2][0] += a.z * bb.x; acc[2][1] += a.z * bb.y; acc[2][2] += a.z * bb.z; acc[2][3] += a.z * bb.w;
      acc[3][0] += a.w * bb.x; acc[3][1] += a.w * bb.y; acc[3][2] += a.w * bb.z; acc[3][3] += a.w * bb.w;
    }
  }
#pragma unroll
  for (int mi = 0; mi < 4; ++mi)
#pragma unroll
    for (int ni = 0; ni < 4; ++ni) {
      const int m = m0 + tj * 4 + mi;
      const int n = n0 + ti * 4 + ni;
      const float v2 = acc[mi][ni] + ldf(bias, bF, n);
      if (mode == 3) {
        dst[(size_t)m * 512 + n] = v2;
      } else {
        const int b = m >> 9, s = m & 511, h = n >> 6, d = n & 63;
        dst[(((size_t)(b * nH + h) * nS) + s) * nD + d] = v2;
      }
    }
}

// ---------------- fused attention: one block per (bh, 16-query tile) --------
// K/V staged in 64-row LDS chunks (coalesced); sc stride 528 (conflict-free).
__global__ __launch_bounds__(256) void attn_kernel(
    const void* __restrict__ qhe, const void* __restrict__ qee,
    const void* __restrict__ khe, const void* __restrict__ kee,
    const int* __restrict__ dist, const int* __restrict__ edge,
    const unsigned char* __restrict__ mraw, const unsigned char* __restrict__ fraw,
    const void* __restrict__ vhe, const void* __restrict__ vee) {
  __shared__ float qtile[16][64];
  __shared__ float ktile[16][64];
  __shared__ float KV[64][65];          // K or V chunk; 65: scalar 2-way max
  __shared__ float sc[16][SCLD];
  __shared__ float chop_s[16][THOP];
  __shared__ float cedge_s[16][TEDGE];
  __shared__ float vha_s[16][THOP];
  __shared__ float vea_s[16][TEDGE];
  __shared__ float red[16][16];
  __shared__ float rowmax_s[16], rowinv_s[16];

  const int qt = blockIdx.x, bh = blockIdx.y;
  const int b = bh >> 3, h = bh & 7;
  const int q0 = qt * 16;
  const int tid = threadIdx.x;

  const int d64 = g_flags[0], e64 = g_flags[1];
  const int mmode = g_flags[2], fmode = g_flags[3];
  const int fqhe = g_flags[7], fqee = g_flags[8];
  const int fkhe = g_flags[9], fkee = g_flags[10];
  const int fvhe = g_flags[11], fvee = g_flags[12];

  for (int i = tid; i < 1024; i += 256) {
    const int r = i >> 6, c = i & 63;
    qtile[r][c] = g_qh[((size_t)bh * nS + q0 + r) * nD + c];
    ktile[r][c] = g_kh[((size_t)bh * nS + q0 + r) * nD + c];
  }
  {
    const int r = tid >> 5, c = tid & 31;
    vha_s[r][c] = 0.f;
    vha_s[8 + r][c] = 0.f;
    vea_s[tid >> 4][tid & 15] = 0.f;
  }
  __syncthreads();

  // ---- Phase 0: chop[q][t], cedge[q][t] ----
  {
    const int q = tid >> 4, c = tid & 15;
#pragma unroll
    for (int tt = 0; tt < 2; ++tt) {
      const int t = c + tt * 16;
      float s1 = 0.f;
      for (int d = 0; d < 64; ++d) {
        const size_t e = (size_t)t * nHID + h * 64 + d;
        s1 += qtile[q][d] * ldf(qhe, fqhe, e) + ktile[q][d] * ldf(khe, fkhe, e);
      }
      chop_s[q][t] = s1;
    }
    float s2 = 0.f;
    for (int d = 0; d < 64; ++d) {
      const size_t e = (size_t)c * nHID + h * 64 + d;
      s2 += qtile[q][d] * ldf(qee, fqee, e) + ktile[q][d] * ldf(kee, fkee, e);
    }
    cedge_s[q][c] = s2;
  }

  // ---- Phase A: scores = (QK^T + gathered bias) * SCALE, masked ----
  {
    const int key_l = tid & 63;          // key within chunk
    const int qg = tid >> 6;             // q group: 4 q's per thread
    for (int kc0 = 0; kc0 < 512; kc0 += 64) {
      __syncthreads();                   // KV reuse guard
#pragma unroll
      for (int i = 0; i < 16; ++i) {
        const int idx = tid + i * 256;
        KV[idx >> 6][idx & 63] =
            g_kh[((size_t)bh * nS + kc0 + (idx >> 6)) * nD + (idx & 63)];
      }
      __syncthreads();
      const int key = kc0 + key_l;
      float acc[4] = {0.f, 0.f, 0.f, 0.f};
#pragma unroll 8
      for (int d = 0; d < 64; ++d) {
        const float kv = KV[key_l][d];
#pragma unroll
        for (int j = 0; j < 4; ++j) acc[j] += qtile[qg * 4 + j][d] * kv;
      }
      const bool kmask = bool_at(mraw, mmode, (size_t)b * nS + key);
#pragma unroll
      for (int j = 0; j < 4; ++j) {
        const int q = qg * 4 + j;
        const size_t off = ((size_t)b * nS + q0 + q) * nS + key;
        const int dv = (d64 ? dist[2 * off] : dist[off]) & (THOP - 1);
        const int ev = (e64 ? edge[2 * off] : edge[off]) & (TEDGE - 1);
        const float s = (acc[j] + chop_s[q][dv] + cedge_s[q][ev]) * SCALE;
        const bool keep = (h < 4) ? kmask : bool_at(fraw, fmode, off);
        sc[q][key] = keep ? s : NEGINF;
      }
    }
  }
  __syncthreads();

  // ---- Phase B: softmax (unnormalized) + bin scatter (dist/edge re-read) ----
  {
    const int row = tid >> 4, c = tid & 15;
    float m = NEGINF;
#pragma unroll
    for (int i = 0; i < 32; ++i) m = fmaxf(m, sc[row][c + 16 * i]);
    red[row][c] = m;
    __syncthreads();
    if (c == 0) {
      float mm = red[row][0];
#pragma unroll
      for (int i = 1; i < 16; ++i) mm = fmaxf(mm, red[row][i]);
      rowmax_s[row] = mm;
    }
    __syncthreads();
    const float M = rowmax_s[row];
    const size_t rowoff = ((size_t)b * nS + q0 + row) * nS;
    float sum = 0.f;
#pragma unroll
    for (int i = 0; i < 32; ++i) {
      const int kx = c + 16 * i;
      const float p = __expf(sc[row][kx] - M);
      sc[row][kx] = p;
      sum += p;
      const size_t off = rowoff + kx;
      const int dv = (d64 ? dist[2 * off] : dist[off]) & (THOP - 1);
      const int ev = (e64 ? edge[2 * off] : edge[off]) & (TEDGE - 1);
      atomicAdd(&vha_s[row][dv], p);
      atomicAdd(&vea_s[row][ev], p);
    }
    red[row][c] = sum;
    __syncthreads();
    if (c == 0) {
      float ss = 0.f;
#pragma unroll
      for (int i = 0; i < 16; ++i) ss += red[row][i];
      rowinv_s[row] = 1.0f / ss;
    }
  }

  // ---- Phase C: x = (P@V + vha@vhopE + vea@vedgeE) / rowsum ----
  {
    const int d = tid & 63, qg = tid >> 6;
    float a4[4] = {0.f, 0.f, 0.f, 0.f};
    for (int kc0 = 0; kc0 < 512; kc0 += 64) {
      __syncthreads();
#pragma unroll
      for (int i = 0; i < 16; ++i) {
        const int idx = tid + i * 256;
        KV[idx >> 6][idx & 63] =
            g_vh[((size_t)bh * nS + kc0 + (idx >> 6)) * nD + (idx & 63)];
      }
      __syncthreads();
#pragma unroll 8
      for (int kk = 0; kk < 64; ++kk) {
        const float vv = KV[kk][d];
#pragma unroll
        for (int j = 0; j < 4; ++j) a4[j] += sc[qg * 4 + j][kc0 + kk] * vv;
      }
    }
#pragma unroll
    for (int j = 0; j < 4; ++j) {
      const int q = qg * 4 + j;
      float val = a4[j];
      for (int t = 0; t < THOP; ++t)
        val += vha_s[q][t] * ldf(vhe, fvhe, (size_t)t * nHID + h * 64 + d);
      for (int t = 0; t < TEDGE; ++t)
        val += vea_s[q][t] * ldf(vee, fvee, (size_t)t * nHID + h * 64 + d);
      val *= rowinv_s[q];
      g_x[((size_t)b * nS + q0 + q) * nHID + h * 64 + d] = val;
    }
  }
}

// ---------------- launcher ----------------
extern "C" void kernel_launch(void* const* d_in, const int* in_sizes, int n_in,
                              void* d_out, int out_size, void* d_ws, size_t ws_size,
                              hipStream_t stream) {
  const void* q   = d_in[0];
  const void* k   = d_in[1];
  const void* v   = d_in[2];
  const void* qhe = d_in[3];
  const void* qee = d_in[4];
  const void* khe = d_in[5];
  const void* kee = d_in[6];
  const void* vhe = d_in[7];
  const void* vee = d_in[8];
  const int* dist = (const int*)d_in[9];
  const int* edge = (const int*)d_in[10];
  const unsigned char* mraw = (const unsigned char*)d_in[11];
  const unsigned char* fraw = (const unsigned char*)d_in[12];
  const void* Wq = d_in[13];
  const void* bq = d_in[14];
  const void* Wk = d_in[15];
  const void* bk = d_in[16];
  const void* Wv = d_in[17];
  const void* bv = d_in[18];
  const void* Wo = d_in[19];
  const void* bo = d_in[20];

  detect_all<<<20, 256, 0, stream>>>(q, k, v, qhe, qee, khe, kee, vhe, vee,
                                     dist, edge, mraw, fraw,
                                     Wq, bq, Wk, bk, Wv, bv, Wo, bo);
  float* qh_d; hipGetSymbolAddress((void**)&qh_d, HIP_SYMBOL(g_qh));
  float* kh_d; hipGetSymbolAddress((void**)&kh_d, HIP_SYMBOL(g_kh));
  float* vh_d; hipGetSymbolAddress((void**)&vh_d, HIP_SYMBOL(g_vh));
  float* x_d;  hipGetSymbolAddress((void**)&x_d,  HIP_SYMBOL(g_x));
  gemm_tiled<<<dim3(8, 64), 256, 0, stream>>>(q, 4, Wq, 13, bq, 14, qh_d, 0);
  gemm_tiled<<<dim3(8, 64), 256, 0, stream>>>(k, 5, Wk, 15, bk, 16, kh_d, 1);
  gemm_tiled<<<dim3(8, 64), 256, 0, stream>>>(v, 6, Wv, 17, bv, 18, vh_d, 2);
  attn_kernel<<<dim3(32, 64), 256, 0, stream>>>(qhe, qee, khe, kee, dist, edge,
                                                mraw, fraw, vhe, vee);
  gemm_tiled<<<dim3(8, 64), 256, 0, stream>>>(x_d, 21, Wo, 19, bo, 20,
                                              (float*)d_out, 3);
}